// Round 2
// baseline (4486.324 us; speedup 1.0000x reference)
//
#include <hip/hip_runtime.h>
#include <math.h>

#define EPS 1e-6f

// One block = strip of 4 adjacent windows (8 rows x 32 cols), computed
// sequentially. All global I/O is full 128B lines via float4 register staging.
// LDS: qkv_lds[192][65] (stride 65: conflict-optimal, b32 only)
//      xwin   [64][68]  (stride 68: 16B-aligned rows for b128 stage/collect)
//      kv[8][8][9], kmean[8][9], sc[64]
__global__ __launch_bounds__(256, 2) void fla_kernel(
    const float* __restrict__ x,        // (8, 64, 256, 256)
    const float* __restrict__ qkv_w,    // (192, 64)
    const float* __restrict__ qkv_b,    // (192,)
    const float* __restrict__ proj_w,   // (64, 64)
    const float* __restrict__ proj_b,   // (64,)
    const float* __restrict__ scale,    // (64,)
    const float* __restrict__ pos_enc,  // (64, 64)
    const float* __restrict__ dwc_w,    // (8, 1, 5, 5)
    const float* __restrict__ dwc_b,    // (8,)
    float* __restrict__ out)            // (8, 64, 256, 256)
{
    __shared__ float qkv_lds[192 * 65];
    __shared__ __align__(16) float xwin[64 * 68];
    __shared__ float kv_lds[8 * 8 * 9];
    __shared__ float kmean_lds[8 * 9];
    __shared__ float sc_lds[64];

    const int t    = threadIdx.x;
    const int lane = t & 63;
    const int w    = __builtin_amdgcn_readfirstlane(t >> 6);   // wave id

    const int bid = blockIdx.x;
    const int b   = bid >> 8;
    const int wi  = (bid >> 3) & 31;
    const int g   = bid & 7;
    const int h0  = wi * 8;
    const int cg  = g * 32;

    const int r   = (t >> 3) & 7;   // row of this thread's pieces
    const int sub = t & 7;          // 4-float column slot within strip row
    const int jx  = sub >> 1;       // which window this thread's pieces belong to
    const int s   = sub & 1;        // low/high half of the window's 8 cols

    if (t < 64) sc_lds[t] = log1pf(expf(scale[t]));   // softplus

    // ---- coalesced global load: 16 float4 pieces/thread (full 128B lines) ----
    const size_t gbase = (((size_t)(b * 64 + w) * 256 + (h0 + r)) * 256) + cg + sub * 4;
    float4 hx[16];
    #pragma unroll
    for (int i = 0; i < 16; ++i)
        hx[i] = *(const float4*)(x + gbase + (size_t)i * 4 * 65536);

    const int n   = t >> 2;     // token for phase C/E
    const int cq  = t & 3;      // channel quarter
    const int c0  = cq * 16;
    const int wsi = n >> 3, wsj = n & 7;

    #pragma unroll 1
    for (int j = 0; j < 4; ++j) {
        // ---- stage this window's x into xwin (only owning threads) ----
        if (jx == j) {
            #pragma unroll
            for (int i = 0; i < 16; ++i)
                *(float4*)&xwin[(i * 4 + w) * 68 + r * 8 + s * 4] = hx[i];
        }
        __syncthreads();

        // ---- Phase B: qkv GEMM. lane = token, wave w -> rows w*48..w*48+47 ----
        float xr[64];
        #pragma unroll
        for (int c = 0; c < 64; ++c) xr[c] = xwin[c * 68 + lane];

        #pragma unroll 1
        for (int mt = 0; mt < 3; ++mt) {
            const int m0 = w * 48 + mt * 16;
            float acc[16];
            #pragma unroll
            for (int mi = 0; mi < 16; ++mi) acc[mi] = qkv_b[m0 + mi];
            #pragma unroll
            for (int mi = 0; mi < 16; ++mi) {
                const float* wrow = qkv_w + (size_t)(m0 + mi) * 64;
                #pragma unroll
                for (int c = 0; c < 64; ++c)
                    acc[mi] = fmaf(xr[c], wrow[c], acc[mi]);
            }
            #pragma unroll
            for (int mi = 0; mi < 16; ++mi)
                qkv_lds[(m0 + mi) * 65 + lane] = acc[mi];
        }
        __syncthreads();

        // ---- Phase C: transforms. thread = (token n, quarter cq) ----
        float q[16], k[16];
        #pragma unroll
        for (int jj = 0; jj < 16; ++jj) {
            q[jj] = qkv_lds[(c0 + jj) * 65 + n];
            k[jj] = qkv_lds[(64 + c0 + jj) * 65 + n] + pos_enc[n * 64 + c0 + jj];
        }
        float sq = 0.f, sk = 0.f;
        #pragma unroll
        for (int jj = 0; jj < 16; ++jj) {
            float scj = sc_lds[c0 + jj];
            q[jj] = (fmaxf(q[jj], 0.f) + EPS) / scj;
            k[jj] = (fmaxf(k[jj], 0.f) + EPS) / scj;
            sq += q[jj] * q[jj];
            sk += k[jj] * k[jj];
        }
        sq += __shfl_xor(sq, 1); sq += __shfl_xor(sq, 2);
        sk += __shfl_xor(sk, 1); sk += __shfl_xor(sk, 2);
        const float qn = sqrtf(sq), kn = sqrtf(sk);

        float sq3 = 0.f, sk3 = 0.f;
        #pragma unroll
        for (int jj = 0; jj < 16; ++jj) {
            q[jj] = q[jj] * q[jj] * q[jj];
            k[jj] = k[jj] * k[jj] * k[jj];
            sq3 += q[jj] * q[jj];
            sk3 += k[jj] * k[jj];
        }
        sq3 += __shfl_xor(sq3, 1); sq3 += __shfl_xor(sq3, 2);
        sk3 += __shfl_xor(sk3, 1); sk3 += __shfl_xor(sk3, 2);
        const float qs = qn / sqrtf(sq3), ks = kn / sqrtf(sk3);
        #pragma unroll
        for (int jj = 0; jj < 16; ++jj) {
            q[jj] *= qs;
            k[jj] *= ks;
            qkv_lds[(64 + c0 + jj) * 65 + n] = k[jj];   // k final back
        }
        __syncthreads();

        // ---- Phase D: kv[h][d][e] and kmean[h][d] ----
        {
            const int d = lane >> 3, e = lane & 7;
            #pragma unroll
            for (int hh = 0; hh < 2; ++hh) {
                const int h = w + hh * 4;
                float acc = 0.f;
                #pragma unroll
                for (int nn = 0; nn < 64; ++nn)
                    acc = fmaf(qkv_lds[(64 + h * 8 + d) * 65 + nn],
                               qkv_lds[(128 + h * 8 + e) * 65 + nn], acc);
                kv_lds[h * 72 + d * 9 + e] = acc * (1.0f / 64.0f);
            }
            if (w == 0) {
                float acc = 0.f;
                #pragma unroll
                for (int nn = 0; nn < 64; ++nn)
                    acc += qkv_lds[(64 + d * 8 + e) * 65 + nn];
                kmean_lds[d * 9 + e] = acc * (1.0f / 64.0f);
            }
        }
        __syncthreads();

        // ---- Phase E: attention out + dwc, out_pre -> qkv_lds rows 0..63 ----
        float outp[16];
        #pragma unroll
        for (int hh = 0; hh < 2; ++hh) {
            const int h = 2 * cq + hh;
            float zden = EPS;
            #pragma unroll
            for (int d = 0; d < 8; ++d)
                zden += q[hh * 8 + d] * kmean_lds[h * 9 + d];
            const float z = 1.0f / zden;
            #pragma unroll
            for (int e = 0; e < 8; ++e) {
                float a = 0.f;
                #pragma unroll
                for (int d = 0; d < 8; ++d)
                    a = fmaf(q[hh * 8 + d], kv_lds[h * 72 + d * 9 + e], a);
                outp[hh * 8 + e] = a * z;
            }
        }
        #pragma unroll
        for (int jj = 0; jj < 16; ++jj) {
            const int c = c0 + jj;
            const int d = jj & 7;
            float acc = dwc_b[d];
            #pragma unroll
            for (int u = 0; u < 5; ++u) {
                const int ii = wsi + u - 2;
                #pragma unroll
                for (int vv = 0; vv < 5; ++vv) {
                    const int jc = wsj + vv - 2;
                    const bool ok = (ii >= 0) & (ii < 8) & (jc >= 0) & (jc < 8);
                    const float val = ok ? qkv_lds[(128 + c) * 65 + (ii & 7) * 8 + (jc & 7)] : 0.f;
                    acc = fmaf(val, dwc_w[d * 25 + u * 5 + vv], acc);
                }
            }
            outp[jj] += acc;
        }
        #pragma unroll
        for (int jj = 0; jj < 16; ++jj)
            qkv_lds[(c0 + jj) * 65 + n] = outp[jj];
        __syncthreads();

        // ---- Phase F: proj -> final into xwin ----
        {
            float facc[16];
            #pragma unroll
            for (int ci = 0; ci < 16; ++ci) facc[ci] = proj_b[w * 16 + ci];
            #pragma unroll
            for (int cb = 0; cb < 4; ++cb) {
                float vin[16];
                #pragma unroll
                for (int cc = 0; cc < 16; ++cc) vin[cc] = qkv_lds[(cb * 16 + cc) * 65 + lane];
                #pragma unroll
                for (int ci = 0; ci < 16; ++ci) {
                    const float* prow = proj_w + (size_t)(w * 16 + ci) * 64 + cb * 16;
                    #pragma unroll
                    for (int cc = 0; cc < 16; ++cc)
                        facc[ci] = fmaf(vin[cc], prow[cc], facc[ci]);
                }
            }
            #pragma unroll
            for (int ci = 0; ci < 16; ++ci)
                xwin[(w * 16 + ci) * 68 + lane] = facc[ci];
        }
        __syncthreads();

        // ---- collect final output pieces back into hx registers ----
        if (jx == j) {
            #pragma unroll
            for (int i = 0; i < 16; ++i)
                hx[i] = *(const float4*)&xwin[(i * 4 + w) * 68 + r * 8 + s * 4];
        }
        __syncthreads();
    }

    // ---- coalesced global store: full 128B lines ----
    #pragma unroll
    for (int i = 0; i < 16; ++i)
        *(float4*)(out + gbase + (size_t)i * 4 * 65536) = hx[i];
}

extern "C" void kernel_launch(void* const* d_in, const int* in_sizes, int n_in,
                              void* d_out, int out_size, void* d_ws, size_t ws_size,
                              hipStream_t stream) {
    const float* x       = (const float*)d_in[0];
    const float* qkv_w   = (const float*)d_in[1];
    const float* qkv_b   = (const float*)d_in[2];
    const float* proj_w  = (const float*)d_in[3];
    const float* proj_b  = (const float*)d_in[4];
    const float* scale   = (const float*)d_in[5];
    const float* pos_enc = (const float*)d_in[6];
    const float* dwc_w   = (const float*)d_in[7];
    const float* dwc_b   = (const float*)d_in[8];
    float* o = (float*)d_out;

    hipLaunchKernelGGL(fla_kernel, dim3(2048), dim3(256), 0, stream,
                       x, qkv_w, qkv_b, proj_w, proj_b, scale, pos_enc, dwc_w, dwc_b, o);
}

// Round 3
// 4354.488 us; speedup vs baseline: 1.0303x; 1.0303x over previous
//
#include <hip/hip_runtime.h>
#include <math.h>

#define EPS 1e-6f

// One block = strip of 4 horizontally-adjacent 8x8 windows (8 rows x 32 cols).
// Windows processed sequentially; x loaded per-window global->LDS (32B-granule
// reads, L2-absorbed: full lines reused across j); outputs stored per-window
// regs->global (32B chunks merge to full dirty lines in the SAME XCD's L2).
// NO register array is live across phases; max array size is 16 -> no scratch.
// LDS: qkv_lds[192][65], xwin[64][66], kv[8][72], kmean[8][9], sc[64] ~= 70KB.
__global__ __launch_bounds__(256, 2) void fla_kernel(
    const float* __restrict__ x,        // (8, 64, 256, 256)
    const float* __restrict__ qkv_w,    // (192, 64)
    const float* __restrict__ qkv_b,    // (192,)
    const float* __restrict__ proj_w,   // (64, 64)
    const float* __restrict__ proj_b,   // (64,)
    const float* __restrict__ scale,    // (64,)
    const float* __restrict__ pos_enc,  // (64, 64)
    const float* __restrict__ dwc_w,    // (8, 1, 5, 5)
    const float* __restrict__ dwc_b,    // (8,)
    float* __restrict__ out)            // (8, 64, 256, 256)
{
    __shared__ float qkv_lds[192 * 65];
    __shared__ float xwin[64 * 66];
    __shared__ float kv_lds[8 * 72];
    __shared__ float kmean_lds[8 * 9];
    __shared__ float sc_lds[64];

    const int t    = threadIdx.x;
    const int lane = t & 63;
    const int w    = __builtin_amdgcn_readfirstlane(t >> 6);   // wave id

    const int bid = blockIdx.x;
    const int b   = bid >> 8;
    const int wi  = (bid >> 3) & 31;
    const int g   = bid & 7;
    const int h0  = wi * 8;
    const int cg  = g * 32;

    if (t < 64) sc_lds[t] = log1pf(expf(scale[t]));   // softplus

    const int n   = t >> 2;     // token for phases C/E
    const int cq  = t & 3;      // channel quarter
    const int c0  = cq * 16;
    const int wsi = n >> 3, wsj = n & 7;
    const int sr  = (t >> 3) & 7;   // stage row  (== lane>>3)
    const int scol = t & 7;         // stage col  (== lane&7)

    #pragma unroll 1
    for (int j = 0; j < 4; ++j) {
        // ---- stage: x window j -> xwin[c][n] directly (no register staging) --
        {
            const float* xj = x + (((size_t)(b * 64 + w) * 256 + (h0 + sr)) * 256)
                                + cg + j * 8 + scol;
            #pragma unroll
            for (int i = 0; i < 16; ++i)
                xwin[(w + 4 * i) * 66 + lane] = xj[(size_t)i * 4 * 65536];
        }
        __syncthreads();

        // ---- Phase B: qkv GEMM. wave w -> rows [w*48, w*48+48), chunked K ----
        #pragma unroll 1
        for (int mt = 0; mt < 3; ++mt) {
            const int m0 = w * 48 + mt * 16;
            float acc[16];
            #pragma unroll
            for (int mi = 0; mi < 16; ++mi) acc[mi] = qkv_b[m0 + mi];
            #pragma unroll
            for (int cb = 0; cb < 4; ++cb) {
                float xr[16];
                #pragma unroll
                for (int cc = 0; cc < 16; ++cc)
                    xr[cc] = xwin[(cb * 16 + cc) * 66 + lane];
                #pragma unroll
                for (int mi = 0; mi < 16; ++mi) {
                    const float* wrow = qkv_w + (size_t)(m0 + mi) * 64 + cb * 16;
                    #pragma unroll
                    for (int cc = 0; cc < 16; ++cc)
                        acc[mi] = fmaf(xr[cc], wrow[cc], acc[mi]);
                }
            }
            #pragma unroll
            for (int mi = 0; mi < 16; ++mi)
                qkv_lds[(m0 + mi) * 65 + lane] = acc[mi];
        }
        __syncthreads();

        // ---- Phase C: transforms. thread = (token n, quarter cq) ----
        float q[16];
        {
            float k[16];
            #pragma unroll
            for (int jj = 0; jj < 16; ++jj) {
                q[jj] = qkv_lds[(c0 + jj) * 65 + n];
                k[jj] = qkv_lds[(64 + c0 + jj) * 65 + n] + pos_enc[n * 64 + c0 + jj];
            }
            float sq = 0.f, sk = 0.f;
            #pragma unroll
            for (int jj = 0; jj < 16; ++jj) {
                float scj = sc_lds[c0 + jj];
                q[jj] = (fmaxf(q[jj], 0.f) + EPS) / scj;
                k[jj] = (fmaxf(k[jj], 0.f) + EPS) / scj;
                sq += q[jj] * q[jj];
                sk += k[jj] * k[jj];
            }
            sq += __shfl_xor(sq, 1); sq += __shfl_xor(sq, 2);
            sk += __shfl_xor(sk, 1); sk += __shfl_xor(sk, 2);
            const float qn = sqrtf(sq), kn = sqrtf(sk);

            float sq3 = 0.f, sk3 = 0.f;
            #pragma unroll
            for (int jj = 0; jj < 16; ++jj) {
                q[jj] = q[jj] * q[jj] * q[jj];
                k[jj] = k[jj] * k[jj] * k[jj];
                sq3 += q[jj] * q[jj];
                sk3 += k[jj] * k[jj];
            }
            sq3 += __shfl_xor(sq3, 1); sq3 += __shfl_xor(sq3, 2);
            sk3 += __shfl_xor(sk3, 1); sk3 += __shfl_xor(sk3, 2);
            const float qs = qn / sqrtf(sq3), ks = kn / sqrtf(sk3);
            #pragma unroll
            for (int jj = 0; jj < 16; ++jj) {
                q[jj] *= qs;
                qkv_lds[(64 + c0 + jj) * 65 + n] = k[jj] * ks;   // k final back
            }
        }
        __syncthreads();

        // ---- Phase D: kv[h][d][e] and kmean[h][d] ----
        {
            const int d = lane >> 3, e = lane & 7;
            #pragma unroll
            for (int hh = 0; hh < 2; ++hh) {
                const int h = w + hh * 4;
                float acc = 0.f;
                #pragma unroll
                for (int nn = 0; nn < 64; ++nn)
                    acc = fmaf(qkv_lds[(64 + h * 8 + d) * 65 + nn],
                               qkv_lds[(128 + h * 8 + e) * 65 + nn], acc);
                kv_lds[h * 72 + d * 9 + e] = acc * (1.0f / 64.0f);
            }
            if (w == 0) {
                float acc = 0.f;
                #pragma unroll
                for (int nn = 0; nn < 64; ++nn)
                    acc += qkv_lds[(64 + d * 8 + e) * 65 + nn];
                kmean_lds[d * 9 + e] = acc * (1.0f / 64.0f);
            }
        }
        __syncthreads();

        // ---- Phase E: attention out + dwc -> out_pre into qkv_lds rows 0..63 --
        {
            float outp[16];
            #pragma unroll
            for (int hh = 0; hh < 2; ++hh) {
                const int h = 2 * cq + hh;
                float zden = EPS;
                #pragma unroll
                for (int d = 0; d < 8; ++d)
                    zden += q[hh * 8 + d] * kmean_lds[h * 9 + d];
                const float z = 1.0f / zden;
                #pragma unroll
                for (int e = 0; e < 8; ++e) {
                    float a = 0.f;
                    #pragma unroll
                    for (int d = 0; d < 8; ++d)
                        a = fmaf(q[hh * 8 + d], kv_lds[h * 72 + d * 9 + e], a);
                    outp[hh * 8 + e] = a * z;
                }
            }
            #pragma unroll
            for (int jj = 0; jj < 16; ++jj) {
                const int c = c0 + jj;
                const int d = jj & 7;
                float acc = dwc_b[d];
                #pragma unroll
                for (int u = 0; u < 5; ++u) {
                    const int ii = wsi + u - 2;
                    #pragma unroll
                    for (int vv = 0; vv < 5; ++vv) {
                        const int jc = wsj + vv - 2;
                        const bool ok = (ii >= 0) & (ii < 8) & (jc >= 0) & (jc < 8);
                        const float val = ok ? qkv_lds[(128 + c) * 65 + (ii & 7) * 8 + (jc & 7)] : 0.f;
                        acc = fmaf(val, dwc_w[d * 25 + u * 5 + vv], acc);
                    }
                }
                outp[jj] += acc;
            }
            #pragma unroll
            for (int jj = 0; jj < 16; ++jj)
                qkv_lds[(c0 + jj) * 65 + n] = outp[jj];
        }
        __syncthreads();

        // ---- Phase F: proj, chunked K; store DIRECTLY to global ----
        {
            float facc[16];
            #pragma unroll
            for (int ci = 0; ci < 16; ++ci) facc[ci] = proj_b[w * 16 + ci];
            #pragma unroll
            for (int cb = 0; cb < 4; ++cb) {
                float vin[16];
                #pragma unroll
                for (int cc = 0; cc < 16; ++cc)
                    vin[cc] = qkv_lds[(cb * 16 + cc) * 65 + lane];
                #pragma unroll
                for (int ci = 0; ci < 16; ++ci) {
                    const float* prow = proj_w + (size_t)(w * 16 + ci) * 64 + cb * 16;
                    #pragma unroll
                    for (int cc = 0; cc < 16; ++cc)
                        facc[ci] = fmaf(vin[cc], prow[cc], facc[ci]);
                }
            }
            float* oj = out + (((size_t)(b * 64 + w * 16) * 256 + (h0 + sr)) * 256)
                            + cg + j * 8 + scol;
            #pragma unroll
            for (int ci = 0; ci < 16; ++ci)
                oj[(size_t)ci * 65536] = facc[ci];
        }
        __syncthreads();   // protect qkv_lds/xwin before next iteration's writes
    }
}

extern "C" void kernel_launch(void* const* d_in, const int* in_sizes, int n_in,
                              void* d_out, int out_size, void* d_ws, size_t ws_size,
                              hipStream_t stream) {
    const float* x       = (const float*)d_in[0];
    const float* qkv_w   = (const float*)d_in[1];
    const float* qkv_b   = (const float*)d_in[2];
    const float* proj_w  = (const float*)d_in[3];
    const float* proj_b  = (const float*)d_in[4];
    const float* scale   = (const float*)d_in[5];
    const float* pos_enc = (const float*)d_in[6];
    const float* dwc_w   = (const float*)d_in[7];
    const float* dwc_b   = (const float*)d_in[8];
    float* o = (float*)d_out;

    hipLaunchKernelGGL(fla_kernel, dim3(2048), dim3(256), 0, stream,
                       x, qkv_w, qkv_b, proj_w, proj_b, scale, pos_enc, dwc_w, dwc_b, o);
}

// Round 4
// 2551.968 us; speedup vs baseline: 1.7580x; 1.7063x over previous
//
#include <hip/hip_runtime.h>
#include <math.h>

#define EPS 1e-6f

// ---------------------------------------------------------------------------
// K1: NCHW -> windowed token-major layout  xT[bw][c][n]
//   bw = b*1024 + wi*32 + wj   (window index), n = (h&7)*8 + (w&7)
// Block = (b, wi, 8-channel group). Reads full 1KB image rows, writes 2KB
// contiguous chunks per window. LDS transpose with +1 float4 row pad.
// ---------------------------------------------------------------------------
__global__ __launch_bounds__(256, 2) void k_win(const float* __restrict__ x,
                                                float* __restrict__ xT) {
    __shared__ float4 a4[8 * 8 * 65];
    const int t = threadIdx.x;
    const int bid = blockIdx.x;
    const int b = bid >> 8, wi = (bid >> 3) & 31, c0 = (bid & 7) * 8;

    #pragma unroll
    for (int i = 0; i < 16; ++i) {
        int f = i * 256 + t;                    // float4 id within 64KB slab
        int c = f >> 9, rem = f & 511, h = rem >> 6, w4 = rem & 63;
        a4[(c * 8 + h) * 65 + w4] =
            *((const float4*)x + ((size_t)((b * 64 + c0 + c) * 256 + wi * 8 + h)) * 64 + w4);
    }
    __syncthreads();
    #pragma unroll
    for (int i = 0; i < 16; ++i) {
        int s = i * 256 + t;
        int wj = s >> 7, c = (s >> 4) & 7, n4 = s & 15;
        int h = n4 >> 1;
        float4 v = a4[(c * 8 + h) * 65 + wj * 2 + (n4 & 1)];
        *((float4*)xT + ((size_t)(b * 1024 + wi * 32 + wj)) * 1024 + (c0 + c) * 16 + n4) = v;
    }
}

// ---------------------------------------------------------------------------
// K3: inverse — oT[bw][c][n] -> NCHW out
// ---------------------------------------------------------------------------
__global__ __launch_bounds__(256, 2) void k_unwin(const float* __restrict__ oT,
                                                  float* __restrict__ out) {
    __shared__ float4 a4[8 * 8 * 65];
    const int t = threadIdx.x;
    const int bid = blockIdx.x;
    const int b = bid >> 8, wi = (bid >> 3) & 31, c0 = (bid & 7) * 8;

    #pragma unroll
    for (int i = 0; i < 16; ++i) {
        int s = i * 256 + t;
        int wj = s >> 7, c = (s >> 4) & 7, n4 = s & 15;
        int h = n4 >> 1;
        a4[(c * 8 + h) * 65 + wj * 2 + (n4 & 1)] =
            *((const float4*)oT + ((size_t)(b * 1024 + wi * 32 + wj)) * 1024 + (c0 + c) * 16 + n4);
    }
    __syncthreads();
    #pragma unroll
    for (int i = 0; i < 16; ++i) {
        int f = i * 256 + t;
        int c = f >> 9, rem = f & 511, h = rem >> 6, w4 = rem & 63;
        *((float4*)out + ((size_t)((b * 64 + c0 + c) * 256 + wi * 8 + h)) * 64 + w4) =
            a4[(c * 8 + h) * 65 + w4];
    }
}

// ---------------------------------------------------------------------------
// K2: per-window compute, in-place on xw = ws + bw*4096 floats.
// All global I/O is 256B-coalesced token-vectors. LDS ~52.8KB -> 3 blocks/CU.
// ---------------------------------------------------------------------------
__global__ __launch_bounds__(256, 2) void fla_core(
    float* __restrict__ xw_all,
    const float* __restrict__ qkv_w, const float* __restrict__ qkv_b,
    const float* __restrict__ proj_w, const float* __restrict__ proj_b,
    const float* __restrict__ scale, const float* __restrict__ pos_enc,
    const float* __restrict__ dwc_w, const float* __restrict__ dwc_b)
{
    __shared__ float qkv_lds[192 * 65];
    __shared__ float kv_lds[8 * 72];
    __shared__ float kmean_lds[8 * 9];
    __shared__ float sc_lds[64];

    const int t    = threadIdx.x;
    const int lane = t & 63;
    const int w    = __builtin_amdgcn_readfirstlane(t >> 6);
    float* xw = xw_all + (size_t)blockIdx.x * 4096;

    if (t < 64) sc_lds[t] = log1pf(expf(scale[t]));

    // ---- hoist x: lane = token, 64 channels in regs (coalesced 256B loads) --
    float xr[64];
    #pragma unroll
    for (int c = 0; c < 64; ++c) xr[c] = xw[c * 64 + lane];

    // ---- Phase B: qkv GEMM. wave w -> rows [w*48, w*48+48) ----
    #pragma unroll 1
    for (int mt = 0; mt < 3; ++mt) {
        const int m0 = w * 48 + mt * 16;
        float acc[16];
        #pragma unroll
        for (int mi = 0; mi < 16; ++mi) acc[mi] = qkv_b[m0 + mi];
        #pragma unroll
        for (int mi = 0; mi < 16; ++mi) {
            const float* wrow = qkv_w + (size_t)(m0 + mi) * 64;
            #pragma unroll
            for (int c = 0; c < 64; ++c)
                acc[mi] = fmaf(xr[c], wrow[c], acc[mi]);
        }
        #pragma unroll
        for (int mi = 0; mi < 16; ++mi)
            qkv_lds[(m0 + mi) * 65 + lane] = acc[mi];
    }
    __syncthreads();

    // ---- Phase C: transforms. thread = (token n, quarter cq) ----
    const int n  = t >> 2;
    const int cq = t & 3;
    const int c0 = cq * 16;
    const int wsi = n >> 3, wsj = n & 7;

    float q[16];
    {
        float k[16];
        #pragma unroll
        for (int jj = 0; jj < 16; ++jj) {
            q[jj] = qkv_lds[(c0 + jj) * 65 + n];
            k[jj] = qkv_lds[(64 + c0 + jj) * 65 + n] + pos_enc[n * 64 + c0 + jj];
        }
        float sq = 0.f, sk = 0.f;
        #pragma unroll
        for (int jj = 0; jj < 16; ++jj) {
            float scj = sc_lds[c0 + jj];
            q[jj] = (fmaxf(q[jj], 0.f) + EPS) / scj;
            k[jj] = (fmaxf(k[jj], 0.f) + EPS) / scj;
            sq += q[jj] * q[jj];
            sk += k[jj] * k[jj];
        }
        sq += __shfl_xor(sq, 1); sq += __shfl_xor(sq, 2);
        sk += __shfl_xor(sk, 1); sk += __shfl_xor(sk, 2);
        const float qn = sqrtf(sq), kn = sqrtf(sk);

        float sq3 = 0.f, sk3 = 0.f;
        #pragma unroll
        for (int jj = 0; jj < 16; ++jj) {
            q[jj] = q[jj] * q[jj] * q[jj];
            k[jj] = k[jj] * k[jj] * k[jj];
            sq3 += q[jj] * q[jj];
            sk3 += k[jj] * k[jj];
        }
        sq3 += __shfl_xor(sq3, 1); sq3 += __shfl_xor(sq3, 2);
        sk3 += __shfl_xor(sk3, 1); sk3 += __shfl_xor(sk3, 2);
        const float qs = qn / sqrtf(sq3), ks = kn / sqrtf(sk3);
        #pragma unroll
        for (int jj = 0; jj < 16; ++jj) {
            q[jj] *= qs;
            qkv_lds[(64 + c0 + jj) * 65 + n] = k[jj] * ks;
        }
    }
    __syncthreads();

    // ---- Phase D: kv[h][d][e] and kmean[h][d] ----
    {
        const int d = lane >> 3, e = lane & 7;
        #pragma unroll
        for (int hh = 0; hh < 2; ++hh) {
            const int h = w + hh * 4;
            float acc = 0.f;
            #pragma unroll
            for (int nn = 0; nn < 64; ++nn)
                acc = fmaf(qkv_lds[(64 + h * 8 + d) * 65 + nn],
                           qkv_lds[(128 + h * 8 + e) * 65 + nn], acc);
            kv_lds[h * 72 + d * 9 + e] = acc * (1.0f / 64.0f);
        }
        if (w == 0) {
            float acc = 0.f;
            #pragma unroll
            for (int nn = 0; nn < 64; ++nn)
                acc += qkv_lds[(64 + d * 8 + e) * 65 + nn];
            kmean_lds[d * 9 + e] = acc * (1.0f / 64.0f);
        }
    }
    __syncthreads();

    // ---- Phase E: attention + dwc -> out_pre into qkv_lds rows 0..63 ----
    {
        float outp[16];
        #pragma unroll
        for (int hh = 0; hh < 2; ++hh) {
            const int h = 2 * cq + hh;
            float zden = EPS;
            #pragma unroll
            for (int d = 0; d < 8; ++d)
                zden += q[hh * 8 + d] * kmean_lds[h * 9 + d];
            const float z = 1.0f / zden;
            #pragma unroll
            for (int e = 0; e < 8; ++e) {
                float a = 0.f;
                #pragma unroll
                for (int d = 0; d < 8; ++d)
                    a = fmaf(q[hh * 8 + d], kv_lds[h * 72 + d * 9 + e], a);
                outp[hh * 8 + e] = a * z;
            }
        }
        #pragma unroll
        for (int jj = 0; jj < 16; ++jj) {
            const int c = c0 + jj;
            const int d = jj & 7;
            float acc = dwc_b[d];
            #pragma unroll
            for (int u = 0; u < 5; ++u) {
                const int ii = wsi + u - 2;
                #pragma unroll
                for (int vv = 0; vv < 5; ++vv) {
                    const int jc = wsj + vv - 2;
                    const bool ok = (ii >= 0) & (ii < 8) & (jc >= 0) & (jc < 8);
                    const float val = ok ? qkv_lds[(128 + c) * 65 + (ii & 7) * 8 + (jc & 7)] : 0.f;
                    acc = fmaf(val, dwc_w[d * 25 + u * 5 + vv], acc);
                }
            }
            outp[jj] += acc;
        }
        #pragma unroll
        for (int jj = 0; jj < 16; ++jj)
            qkv_lds[(c0 + jj) * 65 + n] = outp[jj];
    }
    __syncthreads();

    // ---- Phase F: proj; store in-place to xw (coalesced 256B) ----
    {
        float facc[16];
        #pragma unroll
        for (int ci = 0; ci < 16; ++ci) facc[ci] = proj_b[w * 16 + ci];
        #pragma unroll
        for (int cb = 0; cb < 4; ++cb) {
            float vin[16];
            #pragma unroll
            for (int cc = 0; cc < 16; ++cc)
                vin[cc] = qkv_lds[(cb * 16 + cc) * 65 + lane];
            #pragma unroll
            for (int ci = 0; ci < 16; ++ci) {
                const float* prow = proj_w + (size_t)(w * 16 + ci) * 64 + cb * 16;
                #pragma unroll
                for (int cc = 0; cc < 16; ++cc)
                    facc[ci] = fmaf(vin[cc], prow[cc], facc[ci]);
            }
        }
        #pragma unroll
        for (int ci = 0; ci < 16; ++ci)
            xw[(w * 16 + ci) * 64 + lane] = facc[ci];
    }
}

// ---------------------------------------------------------------------------
// Fallback (ws too small): round-1 single kernel, known-correct.
// ---------------------------------------------------------------------------
__global__ __launch_bounds__(256, 3) void fla_fallback(
    const float* __restrict__ x,
    const float* __restrict__ qkv_w, const float* __restrict__ qkv_b,
    const float* __restrict__ proj_w, const float* __restrict__ proj_b,
    const float* __restrict__ scale, const float* __restrict__ pos_enc,
    const float* __restrict__ dwc_w, const float* __restrict__ dwc_b,
    float* __restrict__ out)
{
    __shared__ float qkv_lds[192 * 65];
    __shared__ float kv_lds[8 * 72];
    __shared__ float kmean_lds[8 * 9];
    __shared__ float sc_lds[64];

    const int t = threadIdx.x, lane = t & 63;
    const int w = __builtin_amdgcn_readfirstlane(t >> 6);
    const int bid = blockIdx.x;
    const int b = bid >> 10, wi = (bid >> 5) & 31, wj = bid & 31;
    const int h0 = wi * 8, w0 = wj * 8;

    if (t < 64) sc_lds[t] = log1pf(expf(scale[t]));

    const int row = lane >> 3, col = lane & 7;
    const float* xbase = x + (((size_t)b * 64) * 256 + (h0 + row)) * 256 + (w0 + col);
    float xr[64];
    #pragma unroll
    for (int c = 0; c < 64; ++c) xr[c] = xbase[(size_t)c * 65536];

    #pragma unroll 1
    for (int mt = 0; mt < 3; ++mt) {
        const int m0 = w * 48 + mt * 16;
        float acc[16];
        #pragma unroll
        for (int mi = 0; mi < 16; ++mi) acc[mi] = qkv_b[m0 + mi];
        #pragma unroll
        for (int mi = 0; mi < 16; ++mi) {
            const float* wrow = qkv_w + (size_t)(m0 + mi) * 64;
            #pragma unroll
            for (int c = 0; c < 64; ++c) acc[mi] = fmaf(xr[c], wrow[c], acc[mi]);
        }
        #pragma unroll
        for (int mi = 0; mi < 16; ++mi) qkv_lds[(m0 + mi) * 65 + lane] = acc[mi];
    }
    __syncthreads();

    const int n = t >> 2, cq = t & 3, c0 = cq * 16;
    const int wsi = n >> 3, wsj = n & 7;
    float q[16];
    {
        float k[16];
        #pragma unroll
        for (int jj = 0; jj < 16; ++jj) {
            q[jj] = qkv_lds[(c0 + jj) * 65 + n];
            k[jj] = qkv_lds[(64 + c0 + jj) * 65 + n] + pos_enc[n * 64 + c0 + jj];
        }
        float sq = 0.f, sk = 0.f;
        #pragma unroll
        for (int jj = 0; jj < 16; ++jj) {
            float scj = sc_lds[c0 + jj];
            q[jj] = (fmaxf(q[jj], 0.f) + EPS) / scj;
            k[jj] = (fmaxf(k[jj], 0.f) + EPS) / scj;
            sq += q[jj] * q[jj]; sk += k[jj] * k[jj];
        }
        sq += __shfl_xor(sq, 1); sq += __shfl_xor(sq, 2);
        sk += __shfl_xor(sk, 1); sk += __shfl_xor(sk, 2);
        const float qn = sqrtf(sq), kn = sqrtf(sk);
        float sq3 = 0.f, sk3 = 0.f;
        #pragma unroll
        for (int jj = 0; jj < 16; ++jj) {
            q[jj] = q[jj] * q[jj] * q[jj];
            k[jj] = k[jj] * k[jj] * k[jj];
            sq3 += q[jj] * q[jj]; sk3 += k[jj] * k[jj];
        }
        sq3 += __shfl_xor(sq3, 1); sq3 += __shfl_xor(sq3, 2);
        sk3 += __shfl_xor(sk3, 1); sk3 += __shfl_xor(sk3, 2);
        const float qs = qn / sqrtf(sq3), ks = kn / sqrtf(sk3);
        #pragma unroll
        for (int jj = 0; jj < 16; ++jj) {
            q[jj] *= qs;
            qkv_lds[(64 + c0 + jj) * 65 + n] = k[jj] * ks;
        }
    }
    __syncthreads();
    {
        const int d = lane >> 3, e = lane & 7;
        #pragma unroll
        for (int hh = 0; hh < 2; ++hh) {
            const int h = w + hh * 4;
            float acc = 0.f;
            #pragma unroll
            for (int nn = 0; nn < 64; ++nn)
                acc = fmaf(qkv_lds[(64 + h * 8 + d) * 65 + nn],
                           qkv_lds[(128 + h * 8 + e) * 65 + nn], acc);
            kv_lds[h * 72 + d * 9 + e] = acc * (1.0f / 64.0f);
        }
        if (w == 0) {
            float acc = 0.f;
            #pragma unroll
            for (int nn = 0; nn < 64; ++nn) acc += qkv_lds[(64 + d * 8 + e) * 65 + nn];
            kmean_lds[d * 9 + e] = acc * (1.0f / 64.0f);
        }
    }
    __syncthreads();
    {
        float outp[16];
        #pragma unroll
        for (int hh = 0; hh < 2; ++hh) {
            const int h = 2 * cq + hh;
            float zden = EPS;
            #pragma unroll
            for (int d = 0; d < 8; ++d) zden += q[hh * 8 + d] * kmean_lds[h * 9 + d];
            const float z = 1.0f / zden;
            #pragma unroll
            for (int e = 0; e < 8; ++e) {
                float a = 0.f;
                #pragma unroll
                for (int d = 0; d < 8; ++d)
                    a = fmaf(q[hh * 8 + d], kv_lds[h * 72 + d * 9 + e], a);
                outp[hh * 8 + e] = a * z;
            }
        }
        #pragma unroll
        for (int jj = 0; jj < 16; ++jj) {
            const int c = c0 + jj, d = jj & 7;
            float acc = dwc_b[d];
            #pragma unroll
            for (int u = 0; u < 5; ++u) {
                const int ii = wsi + u - 2;
                #pragma unroll
                for (int vv = 0; vv < 5; ++vv) {
                    const int jc = wsj + vv - 2;
                    const bool ok = (ii >= 0) & (ii < 8) & (jc >= 0) & (jc < 8);
                    const float val = ok ? qkv_lds[(128 + c) * 65 + (ii & 7) * 8 + (jc & 7)] : 0.f;
                    acc = fmaf(val, dwc_w[d * 25 + u * 5 + vv], acc);
                }
            }
            outp[jj] += acc;
        }
        #pragma unroll
        for (int jj = 0; jj < 16; ++jj) qkv_lds[(c0 + jj) * 65 + n] = outp[jj];
    }
    __syncthreads();
    {
        float facc[16];
        #pragma unroll
        for (int ci = 0; ci < 16; ++ci) facc[ci] = proj_b[w * 16 + ci];
        #pragma unroll
        for (int cb = 0; cb < 4; ++cb) {
            float vin[16];
            #pragma unroll
            for (int cc = 0; cc < 16; ++cc) vin[cc] = qkv_lds[(cb * 16 + cc) * 65 + lane];
            #pragma unroll
            for (int ci = 0; ci < 16; ++ci) {
                const float* prow = proj_w + (size_t)(w * 16 + ci) * 64 + cb * 16;
                #pragma unroll
                for (int cc = 0; cc < 16; ++cc) facc[ci] = fmaf(vin[cc], prow[cc], facc[ci]);
            }
        }
        const int r2 = lane >> 3, c2 = lane & 7;
        float* obase = out + (((size_t)b * 64 + w * 16) * 256 + (h0 + r2)) * 256 + (w0 + c2);
        #pragma unroll
        for (int ci = 0; ci < 16; ++ci) obase[(size_t)ci * 65536] = facc[ci];
    }
}

extern "C" void kernel_launch(void* const* d_in, const int* in_sizes, int n_in,
                              void* d_out, int out_size, void* d_ws, size_t ws_size,
                              hipStream_t stream) {
    const float* x       = (const float*)d_in[0];
    const float* qkv_w   = (const float*)d_in[1];
    const float* qkv_b   = (const float*)d_in[2];
    const float* proj_w  = (const float*)d_in[3];
    const float* proj_b  = (const float*)d_in[4];
    const float* scale   = (const float*)d_in[5];
    const float* pos_enc = (const float*)d_in[6];
    const float* dwc_w   = (const float*)d_in[7];
    const float* dwc_b   = (const float*)d_in[8];
    float* o = (float*)d_out;

    const size_t need = (size_t)8192 * 4096 * sizeof(float);   // 134 MB
    if (ws_size >= need) {
        float* xT = (float*)d_ws;
        hipLaunchKernelGGL(k_win, dim3(2048), dim3(256), 0, stream, x, xT);
        hipLaunchKernelGGL(fla_core, dim3(8192), dim3(256), 0, stream,
                           xT, qkv_w, qkv_b, proj_w, proj_b, scale, pos_enc, dwc_w, dwc_b);
        hipLaunchKernelGGL(k_unwin, dim3(2048), dim3(256), 0, stream, xT, o);
    } else {
        hipLaunchKernelGGL(fla_fallback, dim3(8192), dim3(256), 0, stream,
                           x, qkv_w, qkv_b, proj_w, proj_b, scale, pos_enc, dwc_w, dwc_b, o);
    }
}

// Round 6
// 2431.405 us; speedup vs baseline: 1.8452x; 1.0496x over previous
//
#include <hip/hip_runtime.h>
#include <math.h>

#define EPS 1e-6f

// ---------------------------------------------------------------------------
// K1: NCHW -> windowed token-major layout  xT[bw][c][n]
// ---------------------------------------------------------------------------
__global__ __launch_bounds__(256, 2) void k_win(const float* __restrict__ x,
                                                float* __restrict__ xT) {
    __shared__ float4 a4[8 * 8 * 65];
    const int t = threadIdx.x;
    const int bid = blockIdx.x;
    const int b = bid >> 8, wi = (bid >> 3) & 31, c0 = (bid & 7) * 8;

    #pragma unroll
    for (int i = 0; i < 16; ++i) {
        int f = i * 256 + t;
        int c = f >> 9, rem = f & 511, h = rem >> 6, w4 = rem & 63;
        a4[(c * 8 + h) * 65 + w4] =
            *((const float4*)x + ((size_t)((b * 64 + c0 + c) * 256 + wi * 8 + h)) * 64 + w4);
    }
    __syncthreads();
    #pragma unroll
    for (int i = 0; i < 16; ++i) {
        int s = i * 256 + t;
        int wj = s >> 7, c = (s >> 4) & 7, n4 = s & 15;
        int h = n4 >> 1;
        float4 v = a4[(c * 8 + h) * 65 + wj * 2 + (n4 & 1)];
        *((float4*)xT + ((size_t)(b * 1024 + wi * 32 + wj)) * 1024 + (c0 + c) * 16 + n4) = v;
    }
}

// ---------------------------------------------------------------------------
// K4: inverse — oT[bw][c][n] -> NCHW out
// ---------------------------------------------------------------------------
__global__ __launch_bounds__(256, 2) void k_unwin(const float* __restrict__ oT,
                                                  float* __restrict__ out) {
    __shared__ float4 a4[8 * 8 * 65];
    const int t = threadIdx.x;
    const int bid = blockIdx.x;
    const int b = bid >> 8, wi = (bid >> 3) & 31, c0 = (bid & 7) * 8;

    #pragma unroll
    for (int i = 0; i < 16; ++i) {
        int s = i * 256 + t;
        int wj = s >> 7, c = (s >> 4) & 7, n4 = s & 15;
        int h = n4 >> 1;
        a4[(c * 8 + h) * 65 + wj * 2 + (n4 & 1)] =
            *((const float4*)oT + ((size_t)(b * 1024 + wi * 32 + wj)) * 1024 + (c0 + c) * 16 + n4);
    }
    __syncthreads();
    #pragma unroll
    for (int i = 0; i < 16; ++i) {
        int f = i * 256 + t;
        int c = f >> 9, rem = f & 511, h = rem >> 6, w4 = rem & 63;
        *((float4*)out + ((size_t)((b * 64 + c0 + c) * 256 + wi * 8 + h)) * 64 + w4) =
            a4[(c * 8 + h) * 65 + w4];
    }
}

// ---------------------------------------------------------------------------
// K2: qkv GEMM per window. Weights staged ONCE to LDS (broadcast ds_read_b128),
// x tile 16KB LDS, one barrier, outputs streamed to qkvb[bw][192][64].
// LDS = 16KB + 48KB + 0.75KB -> 2 blocks/CU.
// ---------------------------------------------------------------------------
__global__ __launch_bounds__(256, 2) void k_qkv(
    const float* __restrict__ xT, const float* __restrict__ qkv_w,
    const float* __restrict__ qkv_b, float* __restrict__ qkvb)
{
    __shared__ float  xs[64 * 64];       // [c][n]
    __shared__ float4 wq4[192 * 16];     // [m][c/4]
    __shared__ float  qb[192];

    const int t    = threadIdx.x;
    const int lane = t & 63;
    const int w    = __builtin_amdgcn_readfirstlane(t >> 6);
    const size_t bw = blockIdx.x;

    #pragma unroll
    for (int i = 0; i < 4; ++i)
        ((float4*)xs)[i * 256 + t] = ((const float4*)xT)[bw * 1024 + i * 256 + t];
    #pragma unroll
    for (int i = 0; i < 12; ++i)
        wq4[i * 256 + t] = ((const float4*)qkv_w)[i * 256 + t];
    if (t < 192) qb[t] = qkv_b[t];
    __syncthreads();

    #pragma unroll 1
    for (int mt = 0; mt < 3; ++mt) {
        const int m0 = w * 48 + mt * 16;
        float acc[16];
        #pragma unroll
        for (int mi = 0; mi < 16; ++mi) acc[mi] = qb[m0 + mi];
        #pragma unroll
        for (int cb = 0; cb < 4; ++cb) {
            float xrc[16];
            #pragma unroll
            for (int cc = 0; cc < 16; ++cc)
                xrc[cc] = xs[(cb * 16 + cc) * 64 + lane];
            #pragma unroll
            for (int mi = 0; mi < 16; ++mi) {
                #pragma unroll
                for (int c4 = 0; c4 < 4; ++c4) {
                    float4 wv = wq4[(m0 + mi) * 16 + cb * 4 + c4];
                    acc[mi] = fmaf(xrc[c4 * 4 + 0], wv.x, acc[mi]);
                    acc[mi] = fmaf(xrc[c4 * 4 + 1], wv.y, acc[mi]);
                    acc[mi] = fmaf(xrc[c4 * 4 + 2], wv.z, acc[mi]);
                    acc[mi] = fmaf(xrc[c4 * 4 + 3], wv.w, acc[mi]);
                }
            }
        }
        #pragma unroll
        for (int mi = 0; mi < 16; ++mi)
            qkvb[(bw * 192 + m0 + mi) * 64 + lane] = acc[mi];
    }
}

// ---------------------------------------------------------------------------
// K3: per-window transforms + attention + dwc + proj (proj_w in LDS).
// Reads qkvb[bw][192][64], writes oT[bw][64][64].
// LDS ~= 50 + 16 + 3 KB -> 2 blocks/CU.
// ---------------------------------------------------------------------------
__global__ __launch_bounds__(256, 2) void k_midproj(
    const float* __restrict__ qkvb, float* __restrict__ oT,
    const float* __restrict__ proj_w, const float* __restrict__ proj_b,
    const float* __restrict__ scale, const float* __restrict__ pos_enc,
    const float* __restrict__ dwc_w, const float* __restrict__ dwc_b)
{
    __shared__ float  A[192 * 65];
    __shared__ float4 pw4[64 * 16];
    __shared__ float  pb[64];
    __shared__ float  kv_lds[8 * 72];
    __shared__ float  kmean_lds[8 * 9];
    __shared__ float  sc_lds[64];

    const int t    = threadIdx.x;
    const int lane = t & 63;
    const int w    = __builtin_amdgcn_readfirstlane(t >> 6);
    const size_t bw = blockIdx.x;

    // stage qkv rows (global float4 + scalar LDS writes into stride-65 rows)
    #pragma unroll
    for (int i = 0; i < 12; ++i) {
        int idx4 = i * 256 + t;
        float4 v = ((const float4*)qkvb)[bw * 3072 + idx4];
        int row = idx4 >> 4, col = (idx4 & 15) * 4;
        A[row * 65 + col + 0] = v.x;
        A[row * 65 + col + 1] = v.y;
        A[row * 65 + col + 2] = v.z;
        A[row * 65 + col + 3] = v.w;
    }
    #pragma unroll
    for (int i = 0; i < 4; ++i)
        pw4[i * 256 + t] = ((const float4*)proj_w)[i * 256 + t];
    if (t < 64) {
        pb[t] = proj_b[t];
        sc_lds[t] = log1pf(expf(scale[t]));
    }
    __syncthreads();

    const int n  = t >> 2;
    const int cq = t & 3;
    const int c0 = cq * 16;
    const int wsi = n >> 3, wsj = n & 7;

    // ---- Phase C: transforms ----
    float q[16];
    {
        float k[16];
        #pragma unroll
        for (int jj = 0; jj < 16; ++jj) {
            q[jj] = A[(c0 + jj) * 65 + n];
            k[jj] = A[(64 + c0 + jj) * 65 + n] + pos_enc[n * 64 + c0 + jj];
        }
        float sq = 0.f, sk = 0.f;
        #pragma unroll
        for (int jj = 0; jj < 16; ++jj) {
            float scj = sc_lds[c0 + jj];
            q[jj] = (fmaxf(q[jj], 0.f) + EPS) / scj;
            k[jj] = (fmaxf(k[jj], 0.f) + EPS) / scj;
            sq += q[jj] * q[jj];
            sk += k[jj] * k[jj];
        }
        sq += __shfl_xor(sq, 1); sq += __shfl_xor(sq, 2);
        sk += __shfl_xor(sk, 1); sk += __shfl_xor(sk, 2);
        const float qn = sqrtf(sq), kn = sqrtf(sk);

        float sq3 = 0.f, sk3 = 0.f;
        #pragma unroll
        for (int jj = 0; jj < 16; ++jj) {
            q[jj] = q[jj] * q[jj] * q[jj];
            k[jj] = k[jj] * k[jj] * k[jj];
            sq3 += q[jj] * q[jj];
            sk3 += k[jj] * k[jj];
        }
        sq3 += __shfl_xor(sq3, 1); sq3 += __shfl_xor(sq3, 2);
        sk3 += __shfl_xor(sk3, 1); sk3 += __shfl_xor(sk3, 2);
        const float qs = qn / sqrtf(sq3), ks = kn / sqrtf(sk3);
        #pragma unroll
        for (int jj = 0; jj < 16; ++jj) {
            q[jj] *= qs;
            A[(64 + c0 + jj) * 65 + n] = k[jj] * ks;
        }
    }
    __syncthreads();

    // ---- Phase D: kv and kmean ----
    {
        const int d = lane >> 3, e = lane & 7;
        #pragma unroll
        for (int hh = 0; hh < 2; ++hh) {
            const int h = w + hh * 4;
            float acc = 0.f;
            #pragma unroll
            for (int nn = 0; nn < 64; ++nn)
                acc = fmaf(A[(64 + h * 8 + d) * 65 + nn],
                           A[(128 + h * 8 + e) * 65 + nn], acc);
            kv_lds[h * 72 + d * 9 + e] = acc * (1.0f / 64.0f);
        }
        if (w == 0) {
            float acc = 0.f;
            #pragma unroll
            for (int nn = 0; nn < 64; ++nn)
                acc += A[(64 + d * 8 + e) * 65 + nn];
            kmean_lds[d * 9 + e] = acc * (1.0f / 64.0f);
        }
    }
    __syncthreads();

    // ---- Phase E: attention + dwc -> out_pre into A rows 0..63 ----
    {
        float outp[16];
        #pragma unroll
        for (int hh = 0; hh < 2; ++hh) {
            const int h = 2 * cq + hh;
            float zden = EPS;
            #pragma unroll
            for (int d = 0; d < 8; ++d)
                zden += q[hh * 8 + d] * kmean_lds[h * 9 + d];
            const float z = 1.0f / zden;
            #pragma unroll
            for (int e = 0; e < 8; ++e) {
                float a = 0.f;
                #pragma unroll
                for (int d = 0; d < 8; ++d)
                    a = fmaf(q[hh * 8 + d], kv_lds[h * 72 + d * 9 + e], a);
                outp[hh * 8 + e] = a * z;
            }
        }
        #pragma unroll
        for (int jj = 0; jj < 16; ++jj) {
            const int c = c0 + jj;
            const int d = jj & 7;
            float acc = dwc_b[d];
            #pragma unroll
            for (int u = 0; u < 5; ++u) {
                const int ii = wsi + u - 2;
                #pragma unroll
                for (int vv = 0; vv < 5; ++vv) {
                    const int jc = wsj + vv - 2;
                    const bool ok = (ii >= 0) & (ii < 8) & (jc >= 0) & (jc < 8);
                    const float val = ok ? A[(128 + c) * 65 + (ii & 7) * 8 + (jc & 7)] : 0.f;
                    acc = fmaf(val, dwc_w[d * 25 + u * 5 + vv], acc);
                }
            }
            outp[jj] += acc;
        }
        __syncthreads();
        #pragma unroll
        for (int jj = 0; jj < 16; ++jj)
            A[(c0 + jj) * 65 + n] = outp[jj];
    }
    __syncthreads();

    // ---- Phase F: proj from LDS weights; stream to oT ----
    {
        float facc[16];
        #pragma unroll
        for (int ci = 0; ci < 16; ++ci) facc[ci] = pb[w * 16 + ci];
        #pragma unroll
        for (int cb = 0; cb < 4; ++cb) {
            float vin[16];
            #pragma unroll
            for (int cc = 0; cc < 16; ++cc)
                vin[cc] = A[(cb * 16 + cc) * 65 + lane];
            #pragma unroll
            for (int ci = 0; ci < 16; ++ci) {
                #pragma unroll
                for (int c4 = 0; c4 < 4; ++c4) {
                    float4 wv = pw4[(w * 16 + ci) * 16 + cb * 4 + c4];
                    facc[ci] = fmaf(vin[c4 * 4 + 0], wv.x, facc[ci]);
                    facc[ci] = fmaf(vin[c4 * 4 + 1], wv.y, facc[ci]);
                    facc[ci] = fmaf(vin[c4 * 4 + 2], wv.z, facc[ci]);
                    facc[ci] = fmaf(vin[c4 * 4 + 3], wv.w, facc[ci]);
                }
            }
        }
        #pragma unroll
        for (int ci = 0; ci < 16; ++ci)
            oT[(bw * 64 + w * 16 + ci) * 64 + lane] = facc[ci];
    }
}

// ---------------------------------------------------------------------------
// Tier-2 fallback: round-4 fused core (needs only 134MB ws), known-correct.
// ---------------------------------------------------------------------------
__global__ __launch_bounds__(256, 2) void fla_core(
    float* __restrict__ xw_all,
    const float* __restrict__ qkv_w, const float* __restrict__ qkv_b,
    const float* __restrict__ proj_w, const float* __restrict__ proj_b,
    const float* __restrict__ scale, const float* __restrict__ pos_enc,
    const float* __restrict__ dwc_w, const float* __restrict__ dwc_b)
{
    __shared__ float qkv_lds[192 * 65];
    __shared__ float kv_lds[8 * 72];
    __shared__ float kmean_lds[8 * 9];
    __shared__ float sc_lds[64];

    const int t = threadIdx.x, lane = t & 63;
    const int w = __builtin_amdgcn_readfirstlane(t >> 6);
    float* xw = xw_all + (size_t)blockIdx.x * 4096;

    if (t < 64) sc_lds[t] = log1pf(expf(scale[t]));

    float xr[64];
    #pragma unroll
    for (int c = 0; c < 64; ++c) xr[c] = xw[c * 64 + lane];

    #pragma unroll 1
    for (int mt = 0; mt < 3; ++mt) {
        const int m0 = w * 48 + mt * 16;
        float acc[16];
        #pragma unroll
        for (int mi = 0; mi < 16; ++mi) acc[mi] = qkv_b[m0 + mi];
        #pragma unroll
        for (int mi = 0; mi < 16; ++mi) {
            const float* wrow = qkv_w + (size_t)(m0 + mi) * 64;
            #pragma unroll
            for (int c = 0; c < 64; ++c) acc[mi] = fmaf(xr[c], wrow[c], acc[mi]);
        }
        #pragma unroll
        for (int mi = 0; mi < 16; ++mi) qkv_lds[(m0 + mi) * 65 + lane] = acc[mi];
    }
    __syncthreads();

    const int n = t >> 2, cq = t & 3, c0 = cq * 16;
    const int wsi = n >> 3, wsj = n & 7;
    float q[16];
    {
        float k[16];
        #pragma unroll
        for (int jj = 0; jj < 16; ++jj) {
            q[jj] = qkv_lds[(c0 + jj) * 65 + n];
            k[jj] = qkv_lds[(64 + c0 + jj) * 65 + n] + pos_enc[n * 64 + c0 + jj];
        }
        float sq = 0.f, sk = 0.f;
        #pragma unroll
        for (int jj = 0; jj < 16; ++jj) {
            float scj = sc_lds[c0 + jj];
            q[jj] = (fmaxf(q[jj], 0.f) + EPS) / scj;
            k[jj] = (fmaxf(k[jj], 0.f) + EPS) / scj;
            sq += q[jj] * q[jj]; sk += k[jj] * k[jj];
        }
        sq += __shfl_xor(sq, 1); sq += __shfl_xor(sq, 2);
        sk += __shfl_xor(sk, 1); sk += __shfl_xor(sk, 2);
        const float qn = sqrtf(sq), kn = sqrtf(sk);
        float sq3 = 0.f, sk3 = 0.f;
        #pragma unroll
        for (int jj = 0; jj < 16; ++jj) {
            q[jj] = q[jj] * q[jj] * q[jj];
            k[jj] = k[jj] * k[jj] * k[jj];
            sq3 += q[jj] * q[jj]; sk3 += k[jj] * k[jj];
        }
        sq3 += __shfl_xor(sq3, 1); sq3 += __shfl_xor(sq3, 2);
        sk3 += __shfl_xor(sk3, 1); sk3 += __shfl_xor(sk3, 2);
        const float qs = qn / sqrtf(sq3), ks = kn / sqrtf(sk3);
        #pragma unroll
        for (int jj = 0; jj < 16; ++jj) {
            q[jj] *= qs;
            qkv_lds[(64 + c0 + jj) * 65 + n] = k[jj] * ks;
        }
    }
    __syncthreads();
    {
        const int d = lane >> 3, e = lane & 7;
        #pragma unroll
        for (int hh = 0; hh < 2; ++hh) {
            const int h = w + hh * 4;
            float acc = 0.f;
            #pragma unroll
            for (int nn = 0; nn < 64; ++nn)
                acc = fmaf(qkv_lds[(64 + h * 8 + d) * 65 + nn],
                           qkv_lds[(128 + h * 8 + e) * 65 + nn], acc);
            kv_lds[h * 72 + d * 9 + e] = acc * (1.0f / 64.0f);
        }
        if (w == 0) {
            float acc = 0.f;
            #pragma unroll
            for (int nn = 0; nn < 64; ++nn) acc += qkv_lds[(64 + d * 8 + e) * 65 + nn];
            kmean_lds[d * 9 + e] = acc * (1.0f / 64.0f);
        }
    }
    __syncthreads();
    {
        float outp[16];
        #pragma unroll
        for (int hh = 0; hh < 2; ++hh) {
            const int h = 2 * cq + hh;
            float zden = EPS;
            #pragma unroll
            for (int d = 0; d < 8; ++d) zden += q[hh * 8 + d] * kmean_lds[h * 9 + d];
            const float z = 1.0f / zden;
            #pragma unroll
            for (int e = 0; e < 8; ++e) {
                float a = 0.f;
                #pragma unroll
                for (int d = 0; d < 8; ++d)
                    a = fmaf(q[hh * 8 + d], kv_lds[h * 72 + d * 9 + e], a);
                outp[hh * 8 + e] = a * z;
            }
        }
        #pragma unroll
        for (int jj = 0; jj < 16; ++jj) {
            const int c = c0 + jj, d = jj & 7;
            float acc = dwc_b[d];
            #pragma unroll
            for (int u = 0; u < 5; ++u) {
                const int ii = wsi + u - 2;
                #pragma unroll
                for (int vv = 0; vv < 5; ++vv) {
                    const int jc = wsj + vv - 2;
                    const bool ok = (ii >= 0) & (ii < 8) & (jc >= 0) & (jc < 8);
                    const float val = ok ? qkv_lds[(128 + c) * 65 + (ii & 7) * 8 + (jc & 7)] : 0.f;
                    acc = fmaf(val, dwc_w[d * 25 + u * 5 + vv], acc);
                }
            }
            outp[jj] += acc;
        }
        #pragma unroll
        for (int jj = 0; jj < 16; ++jj) qkv_lds[(c0 + jj) * 65 + n] = outp[jj];
    }
    __syncthreads();
    {
        float facc[16];
        #pragma unroll
        for (int ci = 0; ci < 16; ++ci) facc[ci] = proj_b[w * 16 + ci];
        #pragma unroll
        for (int cb = 0; cb < 4; ++cb) {
            float vin[16];
            #pragma unroll
            for (int cc = 0; cc < 16; ++cc) vin[cc] = qkv_lds[(cb * 16 + cc) * 65 + lane];
            #pragma unroll
            for (int ci = 0; ci < 16; ++ci) {
                const float* prow = proj_w + (size_t)(w * 16 + ci) * 64 + cb * 16;
                #pragma unroll
                for (int cc = 0; cc < 16; ++cc) facc[ci] = fmaf(vin[cc], prow[cc], facc[ci]);
            }
        }
        #pragma unroll
        for (int ci = 0; ci < 16; ++ci)
            xw[(w * 16 + ci) * 64 + lane] = facc[ci];
    }
}

extern "C" void kernel_launch(void* const* d_in, const int* in_sizes, int n_in,
                              void* d_out, int out_size, void* d_ws, size_t ws_size,
                              hipStream_t stream) {
    const float* x       = (const float*)d_in[0];
    const float* qkv_w   = (const float*)d_in[1];
    const float* qkv_b   = (const float*)d_in[2];
    const float* proj_w  = (const float*)d_in[3];
    const float* proj_b  = (const float*)d_in[4];
    const float* scale   = (const float*)d_in[5];
    const float* pos_enc = (const float*)d_in[6];
    const float* dwc_w   = (const float*)d_in[7];
    const float* dwc_b   = (const float*)d_in[8];
    float* o = (float*)d_out;

    const size_t xT_elems  = (size_t)8192 * 4096;     // 134 MB
    const size_t qkv_elems = (size_t)8192 * 12288;    // 403 MB
    const size_t need_new  = (xT_elems + qkv_elems) * sizeof(float);
    const size_t need_old  = xT_elems * sizeof(float);

    if (ws_size >= need_new) {
        float* xT   = (float*)d_ws;            // also reused as oT
        float* qkvb = xT + xT_elems;
        hipLaunchKernelGGL(k_win,     dim3(2048), dim3(256), 0, stream, x, xT);
        hipLaunchKernelGGL(k_qkv,     dim3(8192), dim3(256), 0, stream, xT, qkv_w, qkv_b, qkvb);
        hipLaunchKernelGGL(k_midproj, dim3(8192), dim3(256), 0, stream,
                           qkvb, xT, proj_w, proj_b, scale, pos_enc, dwc_w, dwc_b);
        hipLaunchKernelGGL(k_unwin,   dim3(2048), dim3(256), 0, stream, xT, o);
    } else if (ws_size >= need_old) {
        float* xT = (float*)d_ws;
        hipLaunchKernelGGL(k_win, dim3(2048), dim3(256), 0, stream, x, xT);
        hipLaunchKernelGGL(fla_core, dim3(8192), dim3(256), 0, stream,
                           xT, qkv_w, qkv_b, proj_w, proj_b, scale, pos_enc, dwc_w, dwc_b);
        hipLaunchKernelGGL(k_unwin, dim3(2048), dim3(256), 0, stream, xT, o);
    }
}

// Round 7
// 2015.058 us; speedup vs baseline: 2.2264x; 1.2066x over previous
//
#include <hip/hip_runtime.h>
#include <math.h>

#define EPS 1e-6f

// ---------------------------------------------------------------------------
// K1: NCHW -> windowed token-major layout  xT[bw][c][n]   (proven r4/r6)
// ---------------------------------------------------------------------------
__global__ __launch_bounds__(256, 2) void k_win(const float* __restrict__ x,
                                                float* __restrict__ xT) {
    __shared__ float4 a4[8 * 8 * 65];
    const int t = threadIdx.x;
    const int bid = blockIdx.x;
    const int b = bid >> 8, wi = (bid >> 3) & 31, c0 = (bid & 7) * 8;

    #pragma unroll
    for (int i = 0; i < 16; ++i) {
        int f = i * 256 + t;
        int c = f >> 9, rem = f & 511, h = rem >> 6, w4 = rem & 63;
        a4[(c * 8 + h) * 65 + w4] =
            *((const float4*)x + ((size_t)((b * 64 + c0 + c) * 256 + wi * 8 + h)) * 64 + w4);
    }
    __syncthreads();
    #pragma unroll
    for (int i = 0; i < 16; ++i) {
        int s = i * 256 + t;
        int wj = s >> 7, c = (s >> 4) & 7, n4 = s & 15;
        int h = n4 >> 1;
        float4 v = a4[(c * 8 + h) * 65 + wj * 2 + (n4 & 1)];
        *((float4*)xT + ((size_t)(b * 1024 + wi * 32 + wj)) * 1024 + (c0 + c) * 16 + n4) = v;
    }
}

// ---------------------------------------------------------------------------
// K3: inverse — oT[bw][c][n] -> NCHW out   (proven r4/r6)
// ---------------------------------------------------------------------------
__global__ __launch_bounds__(256, 2) void k_unwin(const float* __restrict__ oT,
                                                  float* __restrict__ out) {
    __shared__ float4 a4[8 * 8 * 65];
    const int t = threadIdx.x;
    const int bid = blockIdx.x;
    const int b = bid >> 8, wi = (bid >> 3) & 31, c0 = (bid & 7) * 8;

    #pragma unroll
    for (int i = 0; i < 16; ++i) {
        int s = i * 256 + t;
        int wj = s >> 7, c = (s >> 4) & 7, n4 = s & 15;
        int h = n4 >> 1;
        a4[(c * 8 + h) * 65 + wj * 2 + (n4 & 1)] =
            *((const float4*)oT + ((size_t)(b * 1024 + wi * 32 + wj)) * 1024 + (c0 + c) * 16 + n4);
    }
    __syncthreads();
    #pragma unroll
    for (int i = 0; i < 16; ++i) {
        int f = i * 256 + t;
        int c = f >> 9, rem = f & 511, h = rem >> 6, w4 = rem & 63;
        *((float4*)out + ((size_t)((b * 64 + c0 + c) * 256 + wi * 8 + h)) * 64 + w4) =
            a4[(c * 8 + h) * 65 + w4];
    }
}

// ---------------------------------------------------------------------------
// K2: fully fused per-window kernel, 512 threads (8 waves), in-place on xT.
// LDS 69.4KB -> 2 blocks/CU = 16 waves/CU (2x round 6). All weights via
// wave-uniform pointers (scalar cache). All LDS patterns <=2-way conflicts.
// ---------------------------------------------------------------------------
__global__ __launch_bounds__(512, 4) void fla_core2(
    float* __restrict__ xw_all,
    const float* __restrict__ qkv_w, const float* __restrict__ qkv_b,
    const float* __restrict__ proj_w, const float* __restrict__ proj_b,
    const float* __restrict__ scale, const float* __restrict__ pos_enc,
    const float* __restrict__ dwc_w, const float* __restrict__ dwc_b)
{
    __shared__ float xs[64 * 65];     // [c][n]; later reused for out_pre
    __shared__ float A[192 * 65];     // q rows 0..63, k 64..127, v 128..191
    __shared__ float kv_lds[8 * 72];  // [h][d*9+e]
    __shared__ float kmean_lds[8 * 9];
    __shared__ float sc_lds[64];

    const int t    = threadIdx.x;
    const int lane = t & 63;
    const int w    = __builtin_amdgcn_readfirstlane(t >> 6);  // wave id 0..7
    float* xw = xw_all + (size_t)blockIdx.x * 4096;

    if (t < 64) sc_lds[t] = log1pf(expf(scale[t]));

    // ---- stage x window: 1024 float4 coalesced, into xs[c][n] stride 65 ----
    #pragma unroll
    for (int i = 0; i < 2; ++i) {
        int idx4 = i * 512 + t;                 // 0..1023
        float4 v = ((const float4*)xw)[idx4];
        int row = idx4 >> 4, col = (idx4 & 15) * 4;
        xs[row * 65 + col + 0] = v.x;
        xs[row * 65 + col + 1] = v.y;
        xs[row * 65 + col + 2] = v.z;
        xs[row * 65 + col + 3] = v.w;
    }
    __syncthreads();

    // ---- Phase B: qkv GEMM. wave w -> rows [w*24, w*24+24); lane = token ----
    {
        float xr[64];
        #pragma unroll
        for (int c = 0; c < 64; ++c) xr[c] = xs[c * 65 + lane];

        #pragma unroll 1
        for (int chunk = 0; chunk < 3; ++chunk) {
            const int m0 = w * 24 + chunk * 8;
            float acc[8];
            #pragma unroll
            for (int mi = 0; mi < 8; ++mi) acc[mi] = qkv_b[m0 + mi];
            #pragma unroll
            for (int mi = 0; mi < 8; ++mi) {
                const float* wrow = qkv_w + (size_t)(m0 + mi) * 64;  // uniform -> s_load
                #pragma unroll
                for (int c = 0; c < 64; ++c)
                    acc[mi] = fmaf(xr[c], wrow[c], acc[mi]);
            }
            #pragma unroll
            for (int mi = 0; mi < 8; ++mi)
                A[(m0 + mi) * 65 + lane] = acc[mi];
        }
    }
    __syncthreads();

    // ---- Phase C: transforms. thread = (n = t>>3, oct = t&7), 8 channels ----
    const int n   = t >> 3;
    const int oct = t & 7;
    const int c0  = oct * 8;

    float q[8];
    {
        float k[8];
        float4 pe0 = *(const float4*)(pos_enc + n * 64 + c0);
        float4 pe1 = *(const float4*)(pos_enc + n * 64 + c0 + 4);
        const float pe[8] = {pe0.x, pe0.y, pe0.z, pe0.w, pe1.x, pe1.y, pe1.z, pe1.w};
        float sq = 0.f, sk = 0.f;
        #pragma unroll
        for (int j = 0; j < 8; ++j) {
            float scj = sc_lds[c0 + j];
            q[j] = (fmaxf(A[(c0 + j) * 65 + n], 0.f) + EPS) / scj;
            k[j] = (fmaxf(A[(64 + c0 + j) * 65 + n] + pe[j], 0.f) + EPS) / scj;
            sq += q[j] * q[j];
            sk += k[j] * k[j];
        }
        sq += __shfl_xor(sq, 1); sq += __shfl_xor(sq, 2); sq += __shfl_xor(sq, 4);
        sk += __shfl_xor(sk, 1); sk += __shfl_xor(sk, 2); sk += __shfl_xor(sk, 4);
        const float qn = sqrtf(sq), kn = sqrtf(sk);

        float sq3 = 0.f, sk3 = 0.f;
        #pragma unroll
        for (int j = 0; j < 8; ++j) {
            q[j] = q[j] * q[j] * q[j];
            k[j] = k[j] * k[j] * k[j];
            sq3 += q[j] * q[j];
            sk3 += k[j] * k[j];
        }
        sq3 += __shfl_xor(sq3, 1); sq3 += __shfl_xor(sq3, 2); sq3 += __shfl_xor(sq3, 4);
        sk3 += __shfl_xor(sk3, 1); sk3 += __shfl_xor(sk3, 2); sk3 += __shfl_xor(sk3, 4);
        const float qs = qn / sqrtf(sq3), ks = kn / sqrtf(sk3);
        #pragma unroll
        for (int j = 0; j < 8; ++j) {
            q[j] *= qs;                                   // final q stays in regs
            A[(64 + c0 + j) * 65 + n] = k[j] * ks;        // final k back to LDS
        }
    }
    __syncthreads();

    // ---- Phase D: kv[h][d][e] + kmean[h][d]. thread = (h=w, d, e) ----
    {
        const int d = (t >> 3) & 7, e = t & 7;
        const float* krow = &A[(64 + w * 8 + d) * 65];
        const float* vrow = &A[(128 + w * 8 + e) * 65];
        float acc = 0.f, ksum = 0.f;
        #pragma unroll
        for (int nn = 0; nn < 64; ++nn) {
            float kk = krow[nn];
            acc = fmaf(kk, vrow[nn], acc);
            ksum += kk;
        }
        kv_lds[w * 72 + d * 9 + e] = acc * (1.0f / 64.0f);
        if (e == 0) kmean_lds[w * 9 + d] = ksum * (1.0f / 64.0f);
    }
    __syncthreads();

    // ---- Phase E: attention (head = oct) + dwc; out_pre -> xs ----
    {
        float outp[8];
        float zden = EPS;
        #pragma unroll
        for (int d = 0; d < 8; ++d)
            zden = fmaf(q[d], kmean_lds[oct * 9 + d], zden);
        const float z = 1.0f / zden;
        #pragma unroll
        for (int e = 0; e < 8; ++e) {
            float a = 0.f;
            #pragma unroll
            for (int d = 0; d < 8; ++d)
                a = fmaf(q[d], kv_lds[oct * 72 + d * 9 + e], a);
            outp[e] = a * z;
        }
        const int wsi = n >> 3, wsj = n & 7;
        #pragma unroll
        for (int j = 0; j < 8; ++j) {
            const int c = c0 + j;                 // c&7 == j (c0 = oct*8)
            float acc = dwc_b[j];
            #pragma unroll
            for (int u = 0; u < 5; ++u) {
                const int ii = wsi + u - 2;
                #pragma unroll
                for (int vv = 0; vv < 5; ++vv) {
                    const int jc = wsj + vv - 2;
                    const bool ok = (ii >= 0) & (ii < 8) & (jc >= 0) & (jc < 8);
                    const float val = ok ? A[(128 + c) * 65 + (ii & 7) * 8 + (jc & 7)] : 0.f;
                    acc = fmaf(val, dwc_w[j * 25 + u * 5 + vv], acc);
                }
            }
            outp[j] += acc;
        }
        __syncthreads();    // xs reads (Phase B) long done; order E-writes vs F-reads
        #pragma unroll
        for (int j = 0; j < 8; ++j)
            xs[(c0 + j) * 65 + n] = outp[j];
    }
    __syncthreads();

    // ---- Phase F: proj. wave w -> co = w*8+ci; lane = token. store in-place --
    {
        float facc[8];
        #pragma unroll
        for (int ci = 0; ci < 8; ++ci) facc[ci] = proj_b[w * 8 + ci];
        #pragma unroll
        for (int cb = 0; cb < 4; ++cb) {
            float vin[16];
            #pragma unroll
            for (int cc = 0; cc < 16; ++cc)
                vin[cc] = xs[(cb * 16 + cc) * 65 + lane];
            #pragma unroll
            for (int ci = 0; ci < 8; ++ci) {
                const float* prow = proj_w + (size_t)(w * 8 + ci) * 64 + cb * 16;  // uniform
                #pragma unroll
                for (int cc = 0; cc < 16; ++cc)
                    facc[ci] = fmaf(vin[cc], prow[cc], facc[ci]);
            }
        }
        #pragma unroll
        for (int ci = 0; ci < 8; ++ci)
            xw[(w * 8 + ci) * 64 + lane] = facc[ci];
    }
}

extern "C" void kernel_launch(void* const* d_in, const int* in_sizes, int n_in,
                              void* d_out, int out_size, void* d_ws, size_t ws_size,
                              hipStream_t stream) {
    const float* x       = (const float*)d_in[0];
    const float* qkv_w   = (const float*)d_in[1];
    const float* qkv_b   = (const float*)d_in[2];
    const float* proj_w  = (const float*)d_in[3];
    const float* proj_b  = (const float*)d_in[4];
    const float* scale   = (const float*)d_in[5];
    const float* pos_enc = (const float*)d_in[6];
    const float* dwc_w   = (const float*)d_in[7];
    const float* dwc_b   = (const float*)d_in[8];
    float* o = (float*)d_out;

    float* xT = (float*)d_ws;   // 134 MB, in-place out
    hipLaunchKernelGGL(k_win,     dim3(2048), dim3(256), 0, stream, x, xT);
    hipLaunchKernelGGL(fla_core2, dim3(8192), dim3(512), 0, stream,
                       xT, qkv_w, qkv_b, proj_w, proj_b, scale, pos_enc, dwc_w, dwc_b);
    hipLaunchKernelGGL(k_unwin,   dim3(2048), dim3(256), 0, stream, xT, o);
}

// Round 9
// 726.347 us; speedup vs baseline: 6.1766x; 2.7742x over previous
//
#include <hip/hip_runtime.h>
#include <math.h>

#define EPS 1e-6f

// ---------------------------------------------------------------------------
// K1: NCHW -> windowed token-major layout  xT[bw][c][n]   (proven r4-r7)
// ---------------------------------------------------------------------------
__global__ __launch_bounds__(256, 2) void k_win(const float* __restrict__ x,
                                                float* __restrict__ xT) {
    __shared__ float4 a4[8 * 8 * 65];
    const int t = threadIdx.x;
    const int bid = blockIdx.x;
    const int b = bid >> 8, wi = (bid >> 3) & 31, c0 = (bid & 7) * 8;

    #pragma unroll
    for (int i = 0; i < 16; ++i) {
        int f = i * 256 + t;
        int c = f >> 9, rem = f & 511, h = rem >> 6, w4 = rem & 63;
        a4[(c * 8 + h) * 65 + w4] =
            *((const float4*)x + ((size_t)((b * 64 + c0 + c) * 256 + wi * 8 + h)) * 64 + w4);
    }
    __syncthreads();
    #pragma unroll
    for (int i = 0; i < 16; ++i) {
        int s = i * 256 + t;
        int wj = s >> 7, c = (s >> 4) & 7, n4 = s & 15;
        int h = n4 >> 1;
        float4 v = a4[(c * 8 + h) * 65 + wj * 2 + (n4 & 1)];
        *((float4*)xT + ((size_t)(b * 1024 + wi * 32 + wj)) * 1024 + (c0 + c) * 16 + n4) = v;
    }
}

// ---------------------------------------------------------------------------
// K3: inverse — oT[bw][c][n] -> NCHW out   (proven r4-r7)
// ---------------------------------------------------------------------------
__global__ __launch_bounds__(256, 2) void k_unwin(const float* __restrict__ oT,
                                                  float* __restrict__ out) {
    __shared__ float4 a4[8 * 8 * 65];
    const int t = threadIdx.x;
    const int bid = blockIdx.x;
    const int b = bid >> 8, wi = (bid >> 3) & 31, c0 = (bid & 7) * 8;

    #pragma unroll
    for (int i = 0; i < 16; ++i) {
        int s = i * 256 + t;
        int wj = s >> 7, c = (s >> 4) & 7, n4 = s & 15;
        int h = n4 >> 1;
        a4[(c * 8 + h) * 65 + wj * 2 + (n4 & 1)] =
            *((const float4*)oT + ((size_t)(b * 1024 + wi * 32 + wj)) * 1024 + (c0 + c) * 16 + n4);
    }
    __syncthreads();
    #pragma unroll
    for (int i = 0; i < 16; ++i) {
        int f = i * 256 + t;
        int c = f >> 9, rem = f & 511, h = rem >> 6, w4 = rem & 63;
        *((float4*)out + ((size_t)((b * 64 + c0 + c) * 256 + wi * 8 + h)) * 64 + w4) =
            a4[(c * 8 + h) * 65 + w4];
    }
}

// ---------------------------------------------------------------------------
// K2: fused per-window kernel, 512 threads. Issue-optimized:
//  - xs token-major [n][c] stride 68 -> Phase B x loads = 16 ds_read_b128
//  - Phase B/F inner loops LDS-free (x/out_pre in regs, weights via s_load)
//  - v transposed into dead xs buffer -> dwc taps = 2 ds_read_b128 each
//  - dwc weights in LDS (broadcast reads), outer loops unroll-1 (small code)
//  - all reg arrays compile-time indexed; VGPR capped 128 (launch_bounds 512,4)
// LDS ~= 71KB -> 2 blocks/CU (16 waves/CU). 5 barriers.
// ---------------------------------------------------------------------------
__global__ __launch_bounds__(512, 4) void fla_core3(
    float* __restrict__ xw_all,
    const float* __restrict__ qkv_w, const float* __restrict__ qkv_b,
    const float* __restrict__ proj_w, const float* __restrict__ proj_b,
    const float* __restrict__ scale, const float* __restrict__ pos_enc,
    const float* __restrict__ dwc_w, const float* __restrict__ dwc_b)
{
    __shared__ float xs[64 * 68];     // token-major x; reused as Vt (v [n][c])
    __shared__ float A[192 * 65];     // q rows 0..63 (later out_pre), k 64..127, v 128..191
    __shared__ float kv_lds[8 * 72];
    __shared__ float kmean_lds[8 * 9];
    __shared__ float sc_lds[64];
    __shared__ float dwc_lds[200];

    const int t    = threadIdx.x;
    const int lane = t & 63;
    const int w    = __builtin_amdgcn_readfirstlane(t >> 6);  // wave 0..7
    float* xw = xw_all + (size_t)blockIdx.x * 4096;

    if (t < 64) sc_lds[t] = log1pf(expf(scale[t]));
    if (t >= 64 && t < 264) dwc_lds[t - 64] = dwc_w[t - 64];

    // ---- stage: xT[c][n] (coalesced float4) -> xs[n][c] token-major ----
    #pragma unroll
    for (int i = 0; i < 2; ++i) {
        int idx4 = i * 512 + t;                 // 0..1023
        float4 v = ((const float4*)xw)[idx4];
        int c = idx4 >> 4, n0 = (idx4 & 15) * 4;
        xs[(n0 + 0) * 68 + c] = v.x;
        xs[(n0 + 1) * 68 + c] = v.y;
        xs[(n0 + 2) * 68 + c] = v.z;
        xs[(n0 + 3) * 68 + c] = v.w;
    }
    __syncthreads();

    // ---- Phase B: qkv GEMM. wave w -> rows [w*24, w*24+24); lane = token ----
    {
        float xr[64];
        #pragma unroll
        for (int i = 0; i < 16; ++i)
            *(float4*)&xr[i * 4] = *(const float4*)&xs[lane * 68 + i * 4];

        #pragma unroll 1
        for (int g = 0; g < 3; ++g) {
            const int m0 = w * 24 + g * 8;
            const float* bb = qkv_b + m0;       // uniform
            float acc[8];
            #pragma unroll
            for (int mi = 0; mi < 8; ++mi) acc[mi] = bb[mi];
            #pragma unroll
            for (int mi = 0; mi < 8; ++mi) {
                const float* wrow = qkv_w + (size_t)(m0 + mi) * 64;  // uniform
                #pragma unroll
                for (int c = 0; c < 64; ++c)
                    acc[mi] = fmaf(xr[c], wrow[c], acc[mi]);
            }
            #pragma unroll
            for (int mi = 0; mi < 8; ++mi)
                A[(m0 + mi) * 65 + lane] = acc[mi];
        }
    }
    __syncthreads();   // A ready; xs reads done (xs becomes Vt)

    // ---- Phase C: transforms; thread = (n = t>>3, oct = t&7) ----
    const int n   = t >> 3;
    const int oct = t & 7;
    const int c0  = oct * 8;

    float q[8];
    {
        // v transpose into Vt (= xs) while it's hot
        float4 va, vb;
        va.x = A[(128 + c0 + 0) * 65 + n]; va.y = A[(128 + c0 + 1) * 65 + n];
        va.z = A[(128 + c0 + 2) * 65 + n]; va.w = A[(128 + c0 + 3) * 65 + n];
        vb.x = A[(128 + c0 + 4) * 65 + n]; vb.y = A[(128 + c0 + 5) * 65 + n];
        vb.z = A[(128 + c0 + 6) * 65 + n]; vb.w = A[(128 + c0 + 7) * 65 + n];
        *(float4*)&xs[n * 68 + c0]     = va;
        *(float4*)&xs[n * 68 + c0 + 4] = vb;

        float k[8];
        float4 pe0 = *(const float4*)(pos_enc + n * 64 + c0);
        float4 pe1 = *(const float4*)(pos_enc + n * 64 + c0 + 4);
        const float pe[8] = {pe0.x, pe0.y, pe0.z, pe0.w, pe1.x, pe1.y, pe1.z, pe1.w};
        float sq = 0.f, sk = 0.f;
        #pragma unroll
        for (int j = 0; j < 8; ++j) {
            float scj = sc_lds[c0 + j];
            q[j] = (fmaxf(A[(c0 + j) * 65 + n], 0.f) + EPS) / scj;
            k[j] = (fmaxf(A[(64 + c0 + j) * 65 + n] + pe[j], 0.f) + EPS) / scj;
            sq += q[j] * q[j];
            sk += k[j] * k[j];
        }
        sq += __shfl_xor(sq, 1); sq += __shfl_xor(sq, 2); sq += __shfl_xor(sq, 4);
        sk += __shfl_xor(sk, 1); sk += __shfl_xor(sk, 2); sk += __shfl_xor(sk, 4);
        const float qn = sqrtf(sq), kn = sqrtf(sk);

        float sq3 = 0.f, sk3 = 0.f;
        #pragma unroll
        for (int j = 0; j < 8; ++j) {
            q[j] = q[j] * q[j] * q[j];
            k[j] = k[j] * k[j] * k[j];
            sq3 += q[j] * q[j];
            sk3 += k[j] * k[j];
        }
        sq3 += __shfl_xor(sq3, 1); sq3 += __shfl_xor(sq3, 2); sq3 += __shfl_xor(sq3, 4);
        sk3 += __shfl_xor(sk3, 1); sk3 += __shfl_xor(sk3, 2); sk3 += __shfl_xor(sk3, 4);
        const float qs = qn / sqrtf(sq3), ks = kn / sqrtf(sk3);
        #pragma unroll
        for (int j = 0; j < 8; ++j) {
            q[j] *= qs;                                   // final q in regs
            A[(64 + c0 + j) * 65 + n] = k[j] * ks;        // final k to LDS
        }
    }
    __syncthreads();   // k-final + Vt ready

    // ---- Phase D: kv[h][d][e] + kmean[h][d]; thread = (h=w, d, e) ----
    {
        const int d = (t >> 3) & 7, e = t & 7;
        const float* krow = &A[(64 + w * 8 + d) * 65];
        const float* vcol = &xs[w * 8 + e];
        float acc = 0.f, ksum = 0.f;
        #pragma unroll 8
        for (int nn = 0; nn < 64; ++nn) {
            float kk = krow[nn];
            acc = fmaf(kk, vcol[nn * 68], acc);
            ksum += kk;
        }
        kv_lds[w * 72 + d * 9 + e] = acc * (1.0f / 64.0f);
        if (e == 0) kmean_lds[w * 9 + d] = ksum * (1.0f / 64.0f);
    }
    __syncthreads();   // kv ready

    // ---- Phase E: attention (head = oct) + dwc (Vt b128 taps) ----
    {
        float outp[8];
        float zden = EPS;
        #pragma unroll
        for (int d = 0; d < 8; ++d)
            zden = fmaf(q[d], kmean_lds[oct * 9 + d], zden);
        const float z = 1.0f / zden;
        #pragma unroll
        for (int e = 0; e < 8; ++e) {
            float a = 0.f;
            #pragma unroll
            for (int d = 0; d < 8; ++d)
                a = fmaf(q[d], kv_lds[oct * 72 + d * 9 + e], a);
            outp[e] = a * z;
        }
        const int wsi = n >> 3, wsj = n & 7;
        #pragma unroll 1
        for (int u = 0; u < 5; ++u) {
            const int ii = wsi + u - 2;
            const bool rok = (ii >= 0) & (ii < 8);
            const int iic = min(max(ii, 0), 7);
            #pragma unroll 1
            for (int vv = 0; vv < 5; ++vv) {
                const int jc = wsj + vv - 2;
                const bool ok = rok & (jc >= 0) & (jc < 8);
                const int jcc = min(max(jc, 0), 7);
                const int pos = iic * 8 + jcc;
                float4 va = *(const float4*)&xs[pos * 68 + c0];
                float4 vb = *(const float4*)&xs[pos * 68 + c0 + 4];
                const float sel = ok ? 1.0f : 0.0f;
                const float* dl = &dwc_lds[u * 5 + vv];   // + j*25, broadcast
                outp[0] = fmaf(va.x * sel, dl[0],   outp[0]);
                outp[1] = fmaf(va.y * sel, dl[25],  outp[1]);
                outp[2] = fmaf(va.z * sel, dl[50],  outp[2]);
                outp[3] = fmaf(va.w * sel, dl[75],  outp[3]);
                outp[4] = fmaf(vb.x * sel, dl[100], outp[4]);
                outp[5] = fmaf(vb.y * sel, dl[125], outp[5]);
                outp[6] = fmaf(vb.z * sel, dl[150], outp[6]);
                outp[7] = fmaf(vb.w * sel, dl[175], outp[7]);
            }
        }
        #pragma unroll
        for (int j = 0; j < 8; ++j)
            outp[j] += dwc_b[j];
        __syncthreads();   // kv/Vt reads everywhere done before q-row overwrite
        #pragma unroll
        for (int j = 0; j < 8; ++j)
            A[(c0 + j) * 65 + n] = outp[j];               // out_pre into q rows
    }
    __syncthreads();

    // ---- Phase F: proj. wave w -> co rows w*8..w*8+7; lane = token ----
    {
        float facc[8];
        const float* pbb = proj_b + w * 8;                // uniform
        #pragma unroll
        for (int ci = 0; ci < 8; ++ci) facc[ci] = pbb[ci];
        #pragma unroll 1
        for (int cb = 0; cb < 4; ++cb) {
            float vin[16];
            #pragma unroll
            for (int cc = 0; cc < 16; ++cc)
                vin[cc] = A[(cb * 16 + cc) * 65 + lane];
            #pragma unroll
            for (int ci = 0; ci < 8; ++ci) {
                const float* prow = proj_w + (size_t)(w * 8 + ci) * 64 + cb * 16;  // uniform
                #pragma unroll
                for (int cc = 0; cc < 16; ++cc)
                    facc[ci] = fmaf(vin[cc], prow[cc], facc[ci]);
            }
        }
        #pragma unroll
        for (int ci = 0; ci < 8; ++ci)
            xw[(w * 8 + ci) * 64 + lane] = facc[ci];      // in-place, coalesced
    }
}

extern "C" void kernel_launch(void* const* d_in, const int* in_sizes, int n_in,
                              void* d_out, int out_size, void* d_ws, size_t ws_size,
                              hipStream_t stream) {
    const float* x       = (const float*)d_in[0];
    const float* qkv_w   = (const float*)d_in[1];
    const float* qkv_b   = (const float*)d_in[2];
    const float* proj_w  = (const float*)d_in[3];
    const float* proj_b  = (const float*)d_in[4];
    const float* scale   = (const float*)d_in[5];
    const float* pos_enc = (const float*)d_in[6];
    const float* dwc_w   = (const float*)d_in[7];
    const float* dwc_b   = (const float*)d_in[8];
    float* o = (float*)d_out;

    float* xT = (float*)d_ws;   // 134 MB, in-place out
    hipLaunchKernelGGL(k_win,     dim3(2048), dim3(256), 0, stream, x, xT);
    hipLaunchKernelGGL(fla_core3, dim3(8192), dim3(512), 0, stream,
                       xT, qkv_w, qkv_b, proj_w, proj_b, scale, pos_enc, dwc_w, dwc_b);
    hipLaunchKernelGGL(k_unwin,   dim3(2048), dim3(256), 0, stream, xT, o);
}